// Round 1
// baseline (5291.668 us; speedup 1.0000x reference)
//
#include <hip/hip_runtime.h>
#include <math.h>

#define N_NODES 50000
#define N_EDGES 800000
#define D 128
#define T_TYPES 8
#define TD 1024              // T * D
#define WT_ELEMS (3 * D * D) // 49152, one transposed GRU weight matrix

// ---------------------------------------------------------------------------
// h[n][d] = emb[x[n]][d]
__global__ void embed_gather(const int* __restrict__ x, const float* __restrict__ emb,
                             float* __restrict__ h) {
    int n = blockIdx.x;
    int d = threadIdx.x;
    h[(size_t)n * D + d] = emb[(size_t)x[n] * D + d];
}

// aggr[n][d] = b_node[node_type[n]][d]
__global__ void aggr_init(const int* __restrict__ nt, const float* __restrict__ b_node,
                          float* __restrict__ aggr) {
    int n = blockIdx.x;
    int d = threadIdx.x;
    aggr[(size_t)n * D + d] = b_node[(size_t)nt[n] * D + d];
}

// Wt[k][f] = W[f][k]  (W is [3D][D] = [384][128])
__global__ void transposeW(const float* __restrict__ W, float* __restrict__ Wt) {
    int idx = blockIdx.x * 256 + threadIdx.x; // 0..49151
    int f = idx >> 7;                          // 0..383
    int k = idx & 127;                         // 0..127
    Wt[(size_t)k * 384 + f] = W[(size_t)f * 128 + k];
}

// ---------------------------------------------------------------------------
// Tiled fp32 GEMM: C[m][n0+n] (+)= sum_k A[m][k] * Wrel[t][k][f]
// where global col gc = n0+n, t = gc>>7, f = gc&127. BM=BN=64, BK=64, 256 thr.
template <bool ACCUM>
__global__ __launch_bounds__(256) void gemm64(const float* __restrict__ A,
                                              const float* __restrict__ Brel,
                                              float* __restrict__ C, int Ccols) {
    __shared__ float As[64][68]; // +4 pad keeps float4 alignment, breaks conflicts
    __shared__ float Bs[64][64];

    const int m0 = blockIdx.x * 64;
    const int n0 = blockIdx.y * 64;
    const int t = n0 >> 7;
    const int f0 = n0 & 127;
    const float* Bbase = Brel + (size_t)t * (D * D) + f0;

    const int tid = threadIdx.x;
    const int tx = tid & 15;  // 0..15 -> 4 cols each
    const int ty = tid >> 4;  // 0..15 -> 4 rows each

    float acc[4][4] = {};

    for (int k0 = 0; k0 < 128; k0 += 64) {
        // load A tile 64x64 (guarded rows)
#pragma unroll
        for (int i = 0; i < 4; ++i) {
            int idx = tid + i * 256;  // 0..1023 float4 slots
            int r = idx >> 4;         // 0..63
            int c4 = idx & 15;        // 0..15
            float4 v = make_float4(0.f, 0.f, 0.f, 0.f);
            if (m0 + r < N_NODES)
                v = *(const float4*)(A + (size_t)(m0 + r) * 128 + k0 + c4 * 4);
            *(float4*)(&As[r][c4 * 4]) = v;
        }
        // load B tile 64x64
#pragma unroll
        for (int i = 0; i < 4; ++i) {
            int idx = tid + i * 256;
            int k = idx >> 4;
            int n4 = idx & 15;
            float4 v = *(const float4*)(Bbase + (size_t)(k0 + k) * 128 + n4 * 4);
            *(float4*)(&Bs[k][n4 * 4]) = v;
        }
        __syncthreads();
#pragma unroll
        for (int k = 0; k < 64; ++k) {
            float a0 = As[ty * 4 + 0][k];
            float a1 = As[ty * 4 + 1][k];
            float a2 = As[ty * 4 + 2][k];
            float a3 = As[ty * 4 + 3][k];
            float4 b = *(const float4*)(&Bs[k][tx * 4]);
            acc[0][0] = fmaf(a0, b.x, acc[0][0]); acc[0][1] = fmaf(a0, b.y, acc[0][1]);
            acc[0][2] = fmaf(a0, b.z, acc[0][2]); acc[0][3] = fmaf(a0, b.w, acc[0][3]);
            acc[1][0] = fmaf(a1, b.x, acc[1][0]); acc[1][1] = fmaf(a1, b.y, acc[1][1]);
            acc[1][2] = fmaf(a1, b.z, acc[1][2]); acc[1][3] = fmaf(a1, b.w, acc[1][3]);
            acc[2][0] = fmaf(a2, b.x, acc[2][0]); acc[2][1] = fmaf(a2, b.y, acc[2][1]);
            acc[2][2] = fmaf(a2, b.z, acc[2][2]); acc[2][3] = fmaf(a2, b.w, acc[2][3]);
            acc[3][0] = fmaf(a3, b.x, acc[3][0]); acc[3][1] = fmaf(a3, b.y, acc[3][1]);
            acc[3][2] = fmaf(a3, b.z, acc[3][2]); acc[3][3] = fmaf(a3, b.w, acc[3][3]);
        }
        __syncthreads();
    }

#pragma unroll
    for (int i = 0; i < 4; ++i) {
        int row = m0 + ty * 4 + i;
        if (row < N_NODES) {
            float* cp = C + (size_t)row * Ccols + n0 + tx * 4;
            if (ACCUM) {
                cp[0] += acc[i][0]; cp[1] += acc[i][1];
                cp[2] += acc[i][2]; cp[3] += acc[i][3];
            } else {
                *(float4*)cp = make_float4(acc[i][0], acc[i][1], acc[i][2], acc[i][3]);
            }
        }
    }
}

// ---------------------------------------------------------------------------
// Big path: per edge, gather Ht[src, type] row and atomicAdd into aggr[dst].
// One wave per edge (4 edges / 256-thread block), float2 per lane.
__global__ void edge_gather_scatter(const int* __restrict__ ei, const int* __restrict__ et,
                                    const float* __restrict__ Ht, float* __restrict__ aggr) {
    int e = blockIdx.x * 4 + (threadIdx.x >> 6);
    if (e >= N_EDGES) return;
    int lane = threadIdx.x & 63;
    int src = ei[e];
    int dst = ei[N_EDGES + e];
    int t = et[e];
    float2 v = ((const float2*)(Ht + (size_t)src * TD + t * D))[lane];
    float* dp = aggr + (size_t)dst * D + lane * 2;
    atomicAdd(dp, v.x);
    atomicAdd(dp + 1, v.y);
}

// Small-ws fallback: scatter raw h[src] into S for edges of one type.
__global__ void edge_scatter_type(const int* __restrict__ ei, const int* __restrict__ et,
                                  const float* __restrict__ h, float* __restrict__ S, int t) {
    int e = blockIdx.x * 4 + (threadIdx.x >> 6);
    if (e >= N_EDGES) return;
    if (et[e] != t) return;
    int lane = threadIdx.x & 63;
    int src = ei[e];
    int dst = ei[N_EDGES + e];
    float2 v = ((const float2*)(h + (size_t)src * D))[lane];
    float* dp = S + (size_t)dst * D + lane * 2;
    atomicAdd(dp, v.x);
    atomicAdd(dp + 1, v.y);
}

// ---------------------------------------------------------------------------
// Fused GRU cell, in-place h update. 16 nodes / 256-thread block.
// Thread (f = tid&127, g = tid>>7) handles 8 nodes at column f.
__global__ __launch_bounds__(256) void gru_kernel(const float* __restrict__ aggr,
                                                  float* __restrict__ h,
                                                  const float* __restrict__ WtI,
                                                  const float* __restrict__ WtH,
                                                  const float* __restrict__ b_ih,
                                                  const float* __restrict__ b_hh) {
    __shared__ float sa[16][128];
    __shared__ float sh[16][128];
    const int node0 = blockIdx.x * 16;
    const int tid = threadIdx.x;

#pragma unroll
    for (int i = 0; i < 2; ++i) {
        int idx = tid + i * 256;  // 0..511 float4 slots over 16x128
        int j = idx >> 5;
        int c4 = idx & 31;
        *(float4*)(&sa[j][c4 * 4]) = *(const float4*)(aggr + (size_t)(node0 + j) * D + c4 * 4);
        *(float4*)(&sh[j][c4 * 4]) = *(const float4*)(h + (size_t)(node0 + j) * D + c4 * 4);
    }
    __syncthreads();

    const int f = tid & 127;
    const int jb = (tid >> 7) * 8;

    const float bR = b_ih[f] + b_hh[f];
    const float bZ = b_ih[D + f] + b_hh[D + f];
    const float bIn = b_ih[2 * D + f];
    const float bHn = b_hh[2 * D + f];

    float accR[8] = {}, accZ[8] = {}, accI[8] = {}, accH[8] = {};

#pragma unroll 2
    for (int k4 = 0; k4 < 32; ++k4) {
        const int k = k4 * 4;
        float a_[8][4], h_[8][4];
#pragma unroll
        for (int j = 0; j < 8; ++j) {
            float4 va = *(const float4*)(&sa[jb + j][k]);
            a_[j][0] = va.x; a_[j][1] = va.y; a_[j][2] = va.z; a_[j][3] = va.w;
            float4 vh = *(const float4*)(&sh[jb + j][k]);
            h_[j][0] = vh.x; h_[j][1] = vh.y; h_[j][2] = vh.z; h_[j][3] = vh.w;
        }
#pragma unroll
        for (int kk = 0; kk < 4; ++kk) {
            const float* wI = WtI + (size_t)(k + kk) * 384 + f;
            const float* wH = WtH + (size_t)(k + kk) * 384 + f;
            float wiR = wI[0], wiZ = wI[128], wiN = wI[256];
            float whR = wH[0], whZ = wH[128], whN = wH[256];
#pragma unroll
            for (int j = 0; j < 8; ++j) {
                accR[j] = fmaf(a_[j][kk], wiR, fmaf(h_[j][kk], whR, accR[j]));
                accZ[j] = fmaf(a_[j][kk], wiZ, fmaf(h_[j][kk], whZ, accZ[j]));
                accI[j] = fmaf(a_[j][kk], wiN, accI[j]);
                accH[j] = fmaf(h_[j][kk], whN, accH[j]);
            }
        }
    }

#pragma unroll
    for (int j = 0; j < 8; ++j) {
        float r = 1.0f / (1.0f + __expf(-(accR[j] + bR)));
        float z = 1.0f / (1.0f + __expf(-(accZ[j] + bZ)));
        float n = tanhf(accI[j] + bIn + r * (accH[j] + bHn));
        float hold = sh[jb + j][f];
        h[(size_t)(node0 + jb + j) * D + f] = (1.0f - z) * n + z * hold;
    }
}

// ---------------------------------------------------------------------------
extern "C" void kernel_launch(void* const* d_in, const int* in_sizes, int n_in,
                              void* d_out, int out_size, void* d_ws, size_t ws_size,
                              hipStream_t stream) {
    const int* x      = (const int*)d_in[0];
    const int* ei     = (const int*)d_in[1];   // [2, E]
    const int* et     = (const int*)d_in[2];
    const int* nt     = (const int*)d_in[3];
    const float* emb  = (const float*)d_in[4];
    const float* Wrel = (const float*)d_in[5]; // [T, D, D]
    const float* b_node = (const float*)d_in[6];
    const float* W_ih = (const float*)d_in[7];
    const float* W_hh = (const float*)d_in[8];
    const float* b_ih = (const float*)d_in[9];
    const float* b_hh = (const float*)d_in[10];

    float* h = (float*)d_out;                  // h lives in d_out the whole time
    float* ws = (float*)d_ws;

    const size_t HT_ELEMS = (size_t)N_NODES * TD;  // 51.2M floats (204.8 MB)
    const size_t ND = (size_t)N_NODES * D;         // 6.4M floats (25.6 MB)
    const size_t need_big = (HT_ELEMS + ND + 2 * WT_ELEMS) * sizeof(float);

    const bool big = (ws_size >= need_big);
    float *Ht = nullptr, *S = nullptr, *aggr, *WtI, *WtH;
    if (big) {
        Ht = ws;
        aggr = ws + HT_ELEMS;
        WtI = aggr + ND;
        WtH = WtI + WT_ELEMS;
    } else {
        S = ws;
        aggr = ws + ND;
        WtI = aggr + ND;
        WtH = WtI + WT_ELEMS;
    }

    transposeW<<<192, 256, 0, stream>>>(W_ih, WtI);
    transposeW<<<192, 256, 0, stream>>>(W_hh, WtH);
    embed_gather<<<N_NODES, 128, 0, stream>>>(x, emb, h);

    for (int it = 0; it < 5; ++it) {
        aggr_init<<<N_NODES, 128, 0, stream>>>(nt, b_node, aggr);
        if (big) {
            dim3 g(782, 16);
            gemm64<false><<<g, 256, 0, stream>>>(h, Wrel, Ht, TD);
            edge_gather_scatter<<<200000, 256, 0, stream>>>(ei, et, Ht, aggr);
        } else {
            for (int t = 0; t < T_TYPES; ++t) {
                hipMemsetAsync(S, 0, ND * sizeof(float), stream);
                edge_scatter_type<<<200000, 256, 0, stream>>>(ei, et, h, S, t);
                dim3 g(782, 2);
                gemm64<true><<<g, 256, 0, stream>>>(S, Wrel + (size_t)t * D * D, aggr, D);
            }
        }
        gru_kernel<<<3125, 256, 0, stream>>>(aggr, h, WtI, WtH, b_ih, b_hh);
    }
}

// Round 2
// 2510.274 us; speedup vs baseline: 2.1080x; 2.1080x over previous
//
#include <hip/hip_runtime.h>
#include <math.h>

#define N_NODES 50000
#define N_EDGES 800000
#define D 128
#define T_TYPES 8
#define TD 1024              // T * D
#define WT_ELEMS (3 * D * D) // 49152, one transposed GRU weight matrix

// ---------------------------------------------------------------------------
// h[n][d] = emb[x[n]][d]
__global__ void embed_gather(const int* __restrict__ x, const float* __restrict__ emb,
                             float* __restrict__ h) {
    int n = blockIdx.x;
    int d = threadIdx.x;
    h[(size_t)n * D + d] = emb[(size_t)x[n] * D + d];
}

// aggr[n][d] = b_node[node_type[n]][d]   (fallback path only)
__global__ void aggr_init(const int* __restrict__ nt, const float* __restrict__ b_node,
                          float* __restrict__ aggr) {
    int n = blockIdx.x;
    int d = threadIdx.x;
    aggr[(size_t)n * D + d] = b_node[(size_t)nt[n] * D + d];
}

// Wt[k][f] = W[f][k]  (W is [3D][D] = [384][128])
__global__ void transposeW(const float* __restrict__ W, float* __restrict__ Wt) {
    int idx = blockIdx.x * 256 + threadIdx.x; // 0..49151
    int f = idx >> 7;                          // 0..383
    int k = idx & 127;                         // 0..127
    Wt[(size_t)k * 384 + f] = W[(size_t)f * 128 + k];
}

// ---------------------------------------------------------------------------
// CSR build over dst
__global__ void count_deg(const int* __restrict__ ei, int* __restrict__ deg) {
    int e = blockIdx.x * 256 + threadIdx.x;
    if (e >= N_EDGES) return;
    atomicAdd(&deg[ei[N_EDGES + e]], 1);
}

// One block, 1024 threads: exclusive prefix of deg -> rs[0..N], copy to cursor.
__global__ __launch_bounds__(1024) void scan_deg(const int* __restrict__ deg,
                                                 int* __restrict__ rs,
                                                 int* __restrict__ cursor) {
    __shared__ int sums[1024];
    const int tid = threadIdx.x;
    const int CH = 49; // 1024*49 = 50176 >= 50000
    const int base = tid * CH;
    int s = 0;
    for (int i = 0; i < CH; ++i) {
        int idx = base + i;
        if (idx < N_NODES) s += deg[idx];
    }
    sums[tid] = s;
    __syncthreads();
    // inclusive Hillis-Steele scan
    for (int ofs = 1; ofs < 1024; ofs <<= 1) {
        int v = (tid >= ofs) ? sums[tid - ofs] : 0;
        __syncthreads();
        sums[tid] += v;
        __syncthreads();
    }
    int run = sums[tid] - s; // exclusive offset for this chunk
    for (int i = 0; i < CH; ++i) {
        int idx = base + i;
        if (idx < N_NODES) {
            rs[idx] = run;
            cursor[idx] = run;
            run += deg[idx];
        }
    }
    if (tid == 0) rs[N_NODES] = N_EDGES;
}

// packed[pos] = (src<<3)|type at a slot within dst's CSR row
__global__ void fill_csr(const int* __restrict__ ei, const int* __restrict__ et,
                         int* __restrict__ cursor, int* __restrict__ packed) {
    int e = blockIdx.x * 256 + threadIdx.x;
    if (e >= N_EDGES) return;
    int dst = ei[N_EDGES + e];
    int pos = atomicAdd(&cursor[dst], 1);
    packed[pos] = (ei[e] << 3) | et[e];
}

// ---------------------------------------------------------------------------
// Tiled fp32 GEMM: C[m][n0+n] (+)= sum_k A[m][k] * Wrel[t][k][f]
template <bool ACCUM>
__global__ __launch_bounds__(256) void gemm64(const float* __restrict__ A,
                                              const float* __restrict__ Brel,
                                              float* __restrict__ C, int Ccols) {
    __shared__ float As[64][68];
    __shared__ float Bs[64][64];

    const int m0 = blockIdx.x * 64;
    const int n0 = blockIdx.y * 64;
    const int t = n0 >> 7;
    const int f0 = n0 & 127;
    const float* Bbase = Brel + (size_t)t * (D * D) + f0;

    const int tid = threadIdx.x;
    const int tx = tid & 15;
    const int ty = tid >> 4;

    float acc[4][4] = {};

    for (int k0 = 0; k0 < 128; k0 += 64) {
#pragma unroll
        for (int i = 0; i < 4; ++i) {
            int idx = tid + i * 256;
            int r = idx >> 4;
            int c4 = idx & 15;
            float4 v = make_float4(0.f, 0.f, 0.f, 0.f);
            if (m0 + r < N_NODES)
                v = *(const float4*)(A + (size_t)(m0 + r) * 128 + k0 + c4 * 4);
            *(float4*)(&As[r][c4 * 4]) = v;
        }
#pragma unroll
        for (int i = 0; i < 4; ++i) {
            int idx = tid + i * 256;
            int k = idx >> 4;
            int n4 = idx & 15;
            float4 v = *(const float4*)(Bbase + (size_t)(k0 + k) * 128 + n4 * 4);
            *(float4*)(&Bs[k][n4 * 4]) = v;
        }
        __syncthreads();
#pragma unroll
        for (int k = 0; k < 64; ++k) {
            float a0 = As[ty * 4 + 0][k];
            float a1 = As[ty * 4 + 1][k];
            float a2 = As[ty * 4 + 2][k];
            float a3 = As[ty * 4 + 3][k];
            float4 b = *(const float4*)(&Bs[k][tx * 4]);
            acc[0][0] = fmaf(a0, b.x, acc[0][0]); acc[0][1] = fmaf(a0, b.y, acc[0][1]);
            acc[0][2] = fmaf(a0, b.z, acc[0][2]); acc[0][3] = fmaf(a0, b.w, acc[0][3]);
            acc[1][0] = fmaf(a1, b.x, acc[1][0]); acc[1][1] = fmaf(a1, b.y, acc[1][1]);
            acc[1][2] = fmaf(a1, b.z, acc[1][2]); acc[1][3] = fmaf(a1, b.w, acc[1][3]);
            acc[2][0] = fmaf(a2, b.x, acc[2][0]); acc[2][1] = fmaf(a2, b.y, acc[2][1]);
            acc[2][2] = fmaf(a2, b.z, acc[2][2]); acc[2][3] = fmaf(a2, b.w, acc[2][3]);
            acc[3][0] = fmaf(a3, b.x, acc[3][0]); acc[3][1] = fmaf(a3, b.y, acc[3][1]);
            acc[3][2] = fmaf(a3, b.z, acc[3][2]); acc[3][3] = fmaf(a3, b.w, acc[3][3]);
        }
        __syncthreads();
    }

#pragma unroll
    for (int i = 0; i < 4; ++i) {
        int row = m0 + ty * 4 + i;
        if (row < N_NODES) {
            float* cp = C + (size_t)row * Ccols + n0 + tx * 4;
            if (ACCUM) {
                cp[0] += acc[i][0]; cp[1] += acc[i][1];
                cp[2] += acc[i][2]; cp[3] += acc[i][3];
            } else {
                *(float4*)cp = make_float4(acc[i][0], acc[i][1], acc[i][2], acc[i][3]);
            }
        }
    }
}

// ---------------------------------------------------------------------------
// CSR aggregation: one wave per dst node, no atomics. Fuses b_node bias.
__global__ __launch_bounds__(256) void aggregate_csr(const int* __restrict__ rs,
                                                     const int* __restrict__ packed,
                                                     const float* __restrict__ Ht,
                                                     const int* __restrict__ nt,
                                                     const float* __restrict__ b_node,
                                                     float* __restrict__ aggr) {
    int n = blockIdx.x * 4 + (threadIdx.x >> 6);
    if (n >= N_NODES) return;
    const int lane = threadIdx.x & 63;
    const int beg = rs[n], end = rs[n + 1];

    float2 acc = make_float2(0.f, 0.f);
    int i = beg;
    // 2-wide software pipeline for memory-level parallelism
    for (; i + 1 < end; i += 2) {
        int pk0 = packed[i];
        int pk1 = packed[i + 1];
        const float2* p0 = (const float2*)(Ht + ((size_t)(pk0 >> 3) << 10) + ((pk0 & 7) << 7));
        const float2* p1 = (const float2*)(Ht + ((size_t)(pk1 >> 3) << 10) + ((pk1 & 7) << 7));
        float2 v0 = p0[lane];
        float2 v1 = p1[lane];
        acc.x += v0.x + v1.x;
        acc.y += v0.y + v1.y;
    }
    if (i < end) {
        int pk = packed[i];
        float2 v = ((const float2*)(Ht + ((size_t)(pk >> 3) << 10) + ((pk & 7) << 7)))[lane];
        acc.x += v.x;
        acc.y += v.y;
    }
    float2 b = ((const float2*)(b_node + (size_t)nt[n] * D))[lane];
    ((float2*)(aggr + (size_t)n * D))[lane] = make_float2(acc.x + b.x, acc.y + b.y);
}

// ---------------------------------------------------------------------------
// Fallback (atomic) aggregation — used only if ws is too small for CSR.
__global__ void edge_gather_scatter(const int* __restrict__ ei, const int* __restrict__ et,
                                    const float* __restrict__ Ht, float* __restrict__ aggr) {
    int e = blockIdx.x * 4 + (threadIdx.x >> 6);
    if (e >= N_EDGES) return;
    int lane = threadIdx.x & 63;
    int src = ei[e];
    int dst = ei[N_EDGES + e];
    int t = et[e];
    float2 v = ((const float2*)(Ht + (size_t)src * TD + t * D))[lane];
    float* dp = aggr + (size_t)dst * D + lane * 2;
    atomicAdd(dp, v.x);
    atomicAdd(dp + 1, v.y);
}

__global__ void edge_scatter_type(const int* __restrict__ ei, const int* __restrict__ et,
                                  const float* __restrict__ h, float* __restrict__ S, int t) {
    int e = blockIdx.x * 4 + (threadIdx.x >> 6);
    if (e >= N_EDGES) return;
    if (et[e] != t) return;
    int lane = threadIdx.x & 63;
    int src = ei[e];
    int dst = ei[N_EDGES + e];
    float2 v = ((const float2*)(h + (size_t)src * D))[lane];
    float* dp = S + (size_t)dst * D + lane * 2;
    atomicAdd(dp, v.x);
    atomicAdd(dp + 1, v.y);
}

// ---------------------------------------------------------------------------
// Fused GRU cell, in-place h update.
__global__ __launch_bounds__(256) void gru_kernel(const float* __restrict__ aggr,
                                                  float* __restrict__ h,
                                                  const float* __restrict__ WtI,
                                                  const float* __restrict__ WtH,
                                                  const float* __restrict__ b_ih,
                                                  const float* __restrict__ b_hh) {
    __shared__ float sa[16][128];
    __shared__ float sh[16][128];
    const int node0 = blockIdx.x * 16;
    const int tid = threadIdx.x;

#pragma unroll
    for (int i = 0; i < 2; ++i) {
        int idx = tid + i * 256;
        int j = idx >> 5;
        int c4 = idx & 31;
        *(float4*)(&sa[j][c4 * 4]) = *(const float4*)(aggr + (size_t)(node0 + j) * D + c4 * 4);
        *(float4*)(&sh[j][c4 * 4]) = *(const float4*)(h + (size_t)(node0 + j) * D + c4 * 4);
    }
    __syncthreads();

    const int f = tid & 127;
    const int jb = (tid >> 7) * 8;

    const float bR = b_ih[f] + b_hh[f];
    const float bZ = b_ih[D + f] + b_hh[D + f];
    const float bIn = b_ih[2 * D + f];
    const float bHn = b_hh[2 * D + f];

    float accR[8] = {}, accZ[8] = {}, accI[8] = {}, accH[8] = {};

#pragma unroll 2
    for (int k4 = 0; k4 < 32; ++k4) {
        const int k = k4 * 4;
        float a_[8][4], h_[8][4];
#pragma unroll
        for (int j = 0; j < 8; ++j) {
            float4 va = *(const float4*)(&sa[jb + j][k]);
            a_[j][0] = va.x; a_[j][1] = va.y; a_[j][2] = va.z; a_[j][3] = va.w;
            float4 vh = *(const float4*)(&sh[jb + j][k]);
            h_[j][0] = vh.x; h_[j][1] = vh.y; h_[j][2] = vh.z; h_[j][3] = vh.w;
        }
#pragma unroll
        for (int kk = 0; kk < 4; ++kk) {
            const float* wI = WtI + (size_t)(k + kk) * 384 + f;
            const float* wH = WtH + (size_t)(k + kk) * 384 + f;
            float wiR = wI[0], wiZ = wI[128], wiN = wI[256];
            float whR = wH[0], whZ = wH[128], whN = wH[256];
#pragma unroll
            for (int j = 0; j < 8; ++j) {
                accR[j] = fmaf(a_[j][kk], wiR, fmaf(h_[j][kk], whR, accR[j]));
                accZ[j] = fmaf(a_[j][kk], wiZ, fmaf(h_[j][kk], whZ, accZ[j]));
                accI[j] = fmaf(a_[j][kk], wiN, accI[j]);
                accH[j] = fmaf(h_[j][kk], whN, accH[j]);
            }
        }
    }

#pragma unroll
    for (int j = 0; j < 8; ++j) {
        float r = 1.0f / (1.0f + __expf(-(accR[j] + bR)));
        float z = 1.0f / (1.0f + __expf(-(accZ[j] + bZ)));
        float n = tanhf(accI[j] + bIn + r * (accH[j] + bHn));
        float hold = sh[jb + j][f];
        h[(size_t)(node0 + jb + j) * D + f] = (1.0f - z) * n + z * hold;
    }
}

// ---------------------------------------------------------------------------
extern "C" void kernel_launch(void* const* d_in, const int* in_sizes, int n_in,
                              void* d_out, int out_size, void* d_ws, size_t ws_size,
                              hipStream_t stream) {
    const int* x      = (const int*)d_in[0];
    const int* ei     = (const int*)d_in[1];   // [2, E]
    const int* et     = (const int*)d_in[2];
    const int* nt     = (const int*)d_in[3];
    const float* emb  = (const float*)d_in[4];
    const float* Wrel = (const float*)d_in[5]; // [T, D, D]
    const float* b_node = (const float*)d_in[6];
    const float* W_ih = (const float*)d_in[7];
    const float* W_hh = (const float*)d_in[8];
    const float* b_ih = (const float*)d_in[9];
    const float* b_hh = (const float*)d_in[10];

    float* h = (float*)d_out;
    float* ws = (float*)d_ws;

    const size_t HT_ELEMS = (size_t)N_NODES * TD;  // 51.2M floats
    const size_t ND = (size_t)N_NODES * D;         // 6.4M floats
    // CSR extras: deg(50000) + cursor(50000) + rs(50016) + packed(800000) ints
    const size_t CSR_INTS = 50000 + 50000 + 50016 + 800000;
    const size_t need_csr = (HT_ELEMS + ND + 2 * WT_ELEMS + CSR_INTS) * sizeof(float);
    const size_t need_big = (HT_ELEMS + ND + 2 * WT_ELEMS) * sizeof(float);

    float *Ht, *aggr, *WtI, *WtH, *S = nullptr;
    int *deg = nullptr, *cursor = nullptr, *rs = nullptr, *packed = nullptr;

    const bool csr = (ws_size >= need_csr);
    const bool big = csr || (ws_size >= need_big);
    if (big) {
        Ht = ws;
        aggr = ws + HT_ELEMS;
        WtI = aggr + ND;
        WtH = WtI + WT_ELEMS;
        if (csr) {
            deg = (int*)(WtH + WT_ELEMS);
            cursor = deg + 50000;
            rs = cursor + 50000;
            packed = rs + 50016;
        }
    } else {
        S = ws;
        aggr = ws + ND;
        WtI = aggr + ND;
        WtH = WtI + WT_ELEMS;
    }

    transposeW<<<192, 256, 0, stream>>>(W_ih, WtI);
    transposeW<<<192, 256, 0, stream>>>(W_hh, WtH);
    embed_gather<<<N_NODES, 128, 0, stream>>>(x, emb, h);

    if (csr) {
        hipMemsetAsync(deg, 0, 50000 * sizeof(int), stream);
        count_deg<<<3125, 256, 0, stream>>>(ei, deg);
        scan_deg<<<1, 1024, 0, stream>>>(deg, rs, cursor);
        fill_csr<<<3125, 256, 0, stream>>>(ei, et, cursor, packed);
    }

    for (int it = 0; it < 5; ++it) {
        if (csr) {
            dim3 g(782, 16);
            gemm64<false><<<g, 256, 0, stream>>>(h, Wrel, Ht, TD);
            aggregate_csr<<<12500, 256, 0, stream>>>(rs, packed, Ht, nt, b_node, aggr);
        } else if (big) {
            aggr_init<<<N_NODES, 128, 0, stream>>>(nt, b_node, aggr);
            dim3 g(782, 16);
            gemm64<false><<<g, 256, 0, stream>>>(h, Wrel, Ht, TD);
            edge_gather_scatter<<<200000, 256, 0, stream>>>(ei, et, Ht, aggr);
        } else {
            aggr_init<<<N_NODES, 128, 0, stream>>>(nt, b_node, aggr);
            for (int t = 0; t < T_TYPES; ++t) {
                hipMemsetAsync(S, 0, ND * sizeof(float), stream);
                edge_scatter_type<<<200000, 256, 0, stream>>>(ei, et, h, S, t);
                dim3 g(782, 2);
                gemm64<true><<<g, 256, 0, stream>>>(S, Wrel + (size_t)t * D * D, aggr, D);
            }
        }
        gru_kernel<<<3125, 256, 0, stream>>>(aggr, h, WtI, WtH, b_ih, b_hh);
    }
}